// Round 10
// baseline (14381.985 us; speedup 1.0000x reference)
//
#include <hip/hip_runtime.h>
#include <hip/hip_bf16.h>
#include <math.h>

// Problem constants (fixed by the reference)
#define T_STEPS 4096
#define N_IN    8192
#define N_OUT   2048

// ---------------------------------------------------------------------------
// FUSED kernel: blocks [0,64) run the ESN recurrence; blocks [64,576) run the
// u_proj GEMM. The recurrence consumes u rows ~64x slower than the GEMM
// produces them, so the GEMM hides entirely under the recurrence.
//   - GEMM m-tile completion signaled via mcnt[bm] (RELEASE-agent RMW after
//     __syncthreads, which drains vmcnt; release flushes the XCD L2).
//   - esn blocks gate on mcnt[t>>7]==16 with an ACQUIRE-agent spin, only at
//     128-step boundaries (usually already satisfied).
//   - No deadlock: GEMM blocks depend on nothing. LDS overlaid to 34.9KB and
//     launch_bounds(256,3) (VGPR<=170) give 3 blocks/CU -> 768 slots >= 576
//     blocks: the whole grid is co-resident regardless of dispatch order.
//   - esn waves run at s_setprio(1): colocated GEMM waves fill their stall
//     shadows instead of competing for issue slots.
// ESN structure = r9 (best, prediction-verified): 64 blocks x 256 thr,
// 32 cols/block, GRP=8, W entries in registers + bank-rotation sort,
// tagged-slot exchange {tag,value}, double-buffered vsh, 1 barrier/step.
// Changes vs r9: chunked setup (ent[8] -> 18.4KB scratch), u-load moved
// AFTER the barrier (off the poll's vmcnt), m-tile gating.
// ---------------------------------------------------------------------------
#define RB    64    // esn blocks (1 per CU)
#define CPB   32    // columns per esn block
#define GRP   8     // lanes per column
#define CAP   288   // nnz capacity per column (mean 204.8, sigma 13.6)
#define KMAX  (CAP / GRP)   // 36 register entries per lane
#define NMT   32    // m-tiles (4096/128)
#define GEMM_BLOCKS 512     // 32 m-tiles x 16 n-tiles

// ---- shared-memory overlay (esn and gemm roles never coexist in a block) --
#define SM_ENT   0                       // u64 ent[8][CAP]   = 18432 B
#define SM_CNTS  18432                   // int cnts[8] (+pad) =   64 B
#define SM_VSH   (18432 + 64)            // f32 vsh[2][N_OUT] = 16384 B
#define SM_BYTES (18432 + 64 + 16384)    // 34880 B
#define SM_GA    0                       // f32 As[16][132] = 8448 B
#define SM_GB    8448                    // f32 Bs[16][132] = 8448 B

__device__ __forceinline__ float fast_tanh(float x) {
    const float ax = fabsf(x);
    const float e  = __expf(2.0f * ax);               // inf for big ax
    const float r  = __builtin_amdgcn_rcpf(e + 1.0f); // rcp(inf)=0 -> tanh=1
    const float t  = 1.0f - 2.0f * r;
    return copysignf(t, x);
}

__global__ __launch_bounds__(256, 3) void esn_fused(
        const float* __restrict__ X,    // [4096, 8192]
        const float* __restrict__ W,    // [2048, 2048]
        const float* __restrict__ Win,  // [8192, 2048]
        float* __restrict__ UO,         // [4096, 2048] u_proj then states
        unsigned long long* vslots,     // 2 x N_OUT tagged slots
        int* mcnt) {                    // NMT m-tile completion counters
    __shared__ __align__(16) char smem[SM_BYTES];
    const int tid = threadIdx.x;

    if (blockIdx.x >= RB) {
        // =================== GEMM role (u_proj = X @ Win) ===================
        float (*As)[132] = reinterpret_cast<float(*)[132]>(smem + SM_GA);
        float (*Bs)[132] = reinterpret_cast<float(*)[132]>(smem + SM_GB);
        const int gb = (int)blockIdx.x - RB;
        const int bm = gb >> 4;            // m-tile: blocks 64..79 -> m0 first
        const int bn = gb & 15;
        const int K = N_IN, N = N_OUT;
        const int tx = tid & 15;
        const int ty = tid >> 4;

        float acc[8][8];
#pragma unroll
        for (int i = 0; i < 8; i++)
#pragma unroll
            for (int jj = 0; jj < 8; jj++) acc[i][jj] = 0.f;

        const float* Xb = X + (size_t)(bm * 128) * K;
        const float* Wb = Win + bn * 128;

        for (int kt = 0; kt < K; kt += 16) {
#pragma unroll
            for (int q = 0; q < 2; q++) {
                const int r  = (tid >> 2) + q * 64;
                const int c4 = (tid & 3) * 4;
                const float4 a4 = *reinterpret_cast<const float4*>(&Xb[(size_t)r * K + kt + c4]);
                As[c4 + 0][r] = a4.x;
                As[c4 + 1][r] = a4.y;
                As[c4 + 2][r] = a4.z;
                As[c4 + 3][r] = a4.w;
            }
#pragma unroll
            for (int q = 0; q < 2; q++) {
                const int r  = (tid >> 5) + q * 8;
                const int c4 = (tid & 31) * 4;
                *reinterpret_cast<float4*>(&Bs[r][c4]) =
                    *reinterpret_cast<const float4*>(&Wb[(size_t)(kt + r) * N + c4]);
            }
            __syncthreads();

#pragma unroll
            for (int k = 0; k < 16; k++) {
                float a[8], bb[8];
#pragma unroll
                for (int i = 0; i < 4; i++) {
                    a[i]     = As[k][ty * 4 + i];
                    a[4 + i] = As[k][64 + ty * 4 + i];
                }
#pragma unroll
                for (int jj = 0; jj < 4; jj++) {
                    bb[jj]     = Bs[k][tx * 4 + jj];
                    bb[4 + jj] = Bs[k][64 + tx * 4 + jj];
                }
#pragma unroll
                for (int i = 0; i < 8; i++)
#pragma unroll
                    for (int jj = 0; jj < 8; jj++)
                        acc[i][jj] = fmaf(a[i], bb[jj], acc[i][jj]);
            }
            __syncthreads();
        }

#pragma unroll
        for (int i = 0; i < 8; i++) {
            const int mr = bm * 128 + ((i < 4) ? (ty * 4 + i) : (64 + ty * 4 + (i - 4)));
            float* Crow = UO + (size_t)mr * N + bn * 128;
            float4 v0 = make_float4(acc[i][0], acc[i][1], acc[i][2], acc[i][3]);
            float4 v1 = make_float4(acc[i][4], acc[i][5], acc[i][6], acc[i][7]);
            *reinterpret_cast<float4*>(&Crow[tx * 4])      = v0;
            *reinterpret_cast<float4*>(&Crow[64 + tx * 4]) = v1;
        }
        __syncthreads();   // drains vmcnt: all C stores complete at L2
        if (tid == 0)      // release: writes back XCD L2, then bumps the flag
            __hip_atomic_fetch_add(&mcnt[bm], 1, __ATOMIC_RELEASE,
                                   __HIP_MEMORY_SCOPE_AGENT);
        return;
    }

    // ======================= ESN recurrence role ===========================
    __builtin_amdgcn_s_setprio(1);   // prefer esn waves over colocated GEMM
    auto ent  = reinterpret_cast<unsigned long long(*)[CAP]>(smem + SM_ENT);
    int* cnts = reinterpret_cast<int*>(smem + SM_CNTS);
    float (*vsh)[N_OUT] = reinterpret_cast<float(*)[N_OUT]>(smem + SM_VSH);

    const int b  = blockIdx.x;
    const int c  = tid >> 3;             // column group 0..31
    const int l  = tid & 7;              // lane within group
    const int j  = b * CPB + c;          // global output column
    const int lw = tid & 63;             // lane within wave (bank rotation)

    // ---------- chunked setup: 4 chunks x 8 columns (32-lane scans) --------
    float wreg[KMAX];
    int   ireg[KMAX];
#pragma unroll 1
    for (int chunk = 0; chunk < 4; ++chunk) {
        const int cs = tid >> 5;         // column-in-chunk 0..7
        const int sl = tid & 31;         // scan lane
        const int jc = b * CPB + chunk * 8 + cs;
        int cnt = 0;
        for (int k = 0; k < N_OUT / 32; ++k)
            cnt += (W[(size_t)(sl + 32 * k) * N_OUT + jc] != 0.f) ? 1 : 0;
        int inc = cnt;
#pragma unroll
        for (int d = 1; d < 32; d <<= 1) {
            int n = __shfl_up(inc, d, 64);
            if (sl >= d) inc += n;       // guarded: no cross-column mixing
        }
        int pos = inc - cnt;
        if (sl == 31) cnts[cs] = inc;
        for (int k = 0; k < N_OUT / 32; ++k) {
            const int i = sl + 32 * k;
            const float w = W[(size_t)i * N_OUT + jc];
            if (w != 0.f) {
                if (pos < CAP)
                    ent[cs][pos] = ((unsigned long long)(unsigned)i << 32) |
                                   __float_as_uint(w);
                pos++;
            }
        }
        __syncthreads();
        if ((tid >> 6) == chunk) {       // wave owning these 8 columns
            const int cc   = c & 7;
            const int ccnt = min(cnts[cc], CAP);
#pragma unroll
            for (int k = 0; k < KMAX; ++k) {
                const int p = l + k * GRP;
                if (p < ccnt) {
                    const unsigned long long e = ent[cc][p];
                    wreg[k] = __uint_as_float((unsigned)e);
                    ireg[k] = (int)(e >> 32);
                } else {
                    wreg[k] = 0.f;       // pad: gathers vsh[0] broadcast, w=0
                    ireg[k] = 0;
                }
            }
        }
        __syncthreads();
    }

    // ---------- bank-rotation sort (odd-even network, deterministic) -------
#pragma unroll
    for (int pass = 0; pass < KMAX; ++pass) {
#pragma unroll
        for (int i = (pass & 1); i + 1 < KMAX; i += 2) {
            const int ka = ((ireg[i]     & 31) - lw) & 31;
            const int kb = ((ireg[i + 1] & 31) - lw) & 31;
            const bool sw = ka > kb;
            const int   ti = sw ? ireg[i] : ireg[i + 1];
            const int   bi = sw ? ireg[i + 1] : ireg[i];
            const float tw = sw ? wreg[i] : wreg[i + 1];
            const float bw = sw ? wreg[i + 1] : wreg[i];
            ireg[i] = bi; ireg[i + 1] = ti;
            wreg[i] = bw; wreg[i + 1] = tw;
        }
    }

    // ---------- sequential scan over T ----------
#pragma unroll 1
    for (int t = 0; t < T_STEPS; t++) {
        // ---- poll tagged slots for v_t (8 slots/thread, pending-only) -----
        unsigned long long* vin = vslots + (size_t)(t & 1) * N_OUT;
        float* dst = vsh[t & 1];
        unsigned long long uq[8];
#pragma unroll
        for (int q = 0; q < 8; q++)
            uq[q] = __hip_atomic_load(&vin[tid + q * 256], __ATOMIC_RELAXED,
                                      __HIP_MEMORY_SCOPE_AGENT);
        unsigned pend = 0xFFu;
#pragma unroll 1
        while (true) {
            unsigned np = 0;
#pragma unroll
            for (int q = 0; q < 8; q++) {
                if (pend & (1u << q)) {
                    if ((unsigned)(uq[q] >> 32) == (unsigned)t)
                        dst[tid + q * 256] = __uint_as_float((unsigned)uq[q]);
                    else
                        np |= (1u << q);
                }
            }
            pend = np;
            if (!pend) break;
#pragma unroll
            for (int q = 0; q < 8; q++)
                if (pend & (1u << q))
                    uq[q] = __hip_atomic_load(&vin[tid + q * 256], __ATOMIC_RELAXED,
                                              __HIP_MEMORY_SCOPE_AGENT);
        }
        __syncthreads();   // vsh[t&1] complete (single barrier per step)

        // ---- gate on u-producer at m-tile boundaries (uniform, rare) ------
        if ((t & 127) == 0) {
            while (__hip_atomic_load(&mcnt[t >> 7], __ATOMIC_ACQUIRE,
                                     __HIP_MEMORY_SCOPE_AGENT) < 16) { }
        }
        // u load AFTER the barrier: off the poll's vmcnt, hides under the MAC
        float u = 0.f;
        if (l == 0) u = UO[(size_t)t * N_OUT + j];

        // ---- MAC from registers: 36 bank-scheduled LDS gathers, 4 accums --
        const float* vcur = vsh[t & 1];
        float y0 = 0.f, y1 = 0.f, y2 = 0.f, y3 = 0.f;
#pragma unroll
        for (int k = 0; k < KMAX; k += 4) {
            y0 = fmaf(wreg[k + 0], vcur[ireg[k + 0]], y0);
            y1 = fmaf(wreg[k + 1], vcur[ireg[k + 1]], y1);
            y2 = fmaf(wreg[k + 2], vcur[ireg[k + 2]], y2);
            y3 = fmaf(wreg[k + 3], vcur[ireg[k + 3]], y3);
        }
        float y = (y0 + y1) + (y2 + y3);
#pragma unroll
        for (int d = GRP / 2; d >= 1; d >>= 1) y += __shfl_xor(y, d, 64);

        if (l == 0) {
            const float vnew = 0.5f * vcur[j] + 0.5f * fast_tanh(y + u);
            // slot store FIRST (inter-block critical path), then the output
            const unsigned long long slot =
                ((unsigned long long)(unsigned)(t + 1) << 32) | __float_as_uint(vnew);
            __hip_atomic_store(&vslots[(size_t)((t + 1) & 1) * N_OUT + j], slot,
                               __ATOMIC_RELAXED, __HIP_MEMORY_SCOPE_AGENT);
            UO[(size_t)t * N_OUT + j] = vnew;
        }
        // no trailing barrier: next step touches only vsh[(t+1)&1]
        // (producing v_{t+1} requires all of v_t read -> parity reuse safe)
    }
}

// ---------------------------------------------------------------------------
extern "C" void kernel_launch(void* const* d_in, const int* in_sizes, int n_in,
                              void* d_out, int out_size, void* d_ws, size_t ws_size,
                              hipStream_t stream) {
    const float* x   = (const float*)d_in[0];   // [4096, 8192]
    const float* W   = (const float*)d_in[1];   // [2048, 2048]
    const float* Win = (const float*)d_in[2];   // [8192, 2048]
    float* out = (float*)d_out;                 // [4096, 2048]

    unsigned long long* vslots = (unsigned long long*)d_ws;  // 2 x N_OUT x 8B
    int* mcnt = (int*)((char*)d_ws + 2 * N_OUT * sizeof(unsigned long long));

    // zero slots (tag0 = zero state) + m-tile counters, every launch
    hipMemsetAsync(d_ws, 0,
                   2 * N_OUT * sizeof(unsigned long long) + NMT * sizeof(int),
                   stream);

    esn_fused<<<RB + GEMM_BLOCKS, 256, 0, stream>>>(x, W, Win, out, vslots, mcnt);
}

// Round 11
// 12829.379 us; speedup vs baseline: 1.1210x; 1.1210x over previous
//
#include <hip/hip_runtime.h>
#include <hip/hip_bf16.h>
#include <math.h>

// Problem constants (fixed by the reference)
#define T_STEPS 4096
#define N_IN    8192
#define N_OUT   2048

// ---------------------------------------------------------------------------
// Kernel 1: u_proj = x @ Win   (f32 vector GEMM, 128x128 tile, BK=32)
//   BK=16 -> 32: half the barrier/stall boundaries (256 iters), 2x compute
//   per staged byte. LDS 33.8KB -> still 2+ blocks/CU.
// ---------------------------------------------------------------------------
#define GM_BK 32

__global__ __launch_bounds__(256) void gemm_xwin(const float* __restrict__ X,
                                                 const float* __restrict__ Win,
                                                 float* __restrict__ U) {
    const int K = N_IN, N = N_OUT;
    __shared__ float As[GM_BK][128 + 4];   // transposed A tile: As[k][m]
    __shared__ float Bs[GM_BK][128 + 4];

    const int tid = threadIdx.x;
    const int bm = blockIdx.x;
    const int bn = blockIdx.y;
    const int tx = tid & 15;
    const int ty = tid >> 4;

    float acc[8][8];
#pragma unroll
    for (int i = 0; i < 8; i++)
#pragma unroll
        for (int j = 0; j < 8; j++) acc[i][j] = 0.f;

    const float* Xb = X + (size_t)(bm * 128) * K;
    const float* Wb = Win + bn * 128;

    for (int kt = 0; kt < K; kt += GM_BK) {
        // ---- stage A (128 rows x 32 k), transposed into As[k][m] ----
#pragma unroll
        for (int q = 0; q < 4; q++) {
            const int r  = (tid >> 3) + q * 32;       // 0..127
            const int c4 = (tid & 7) * 4;             // 0..28
            const float4 a4 = *reinterpret_cast<const float4*>(&Xb[(size_t)r * K + kt + c4]);
            As[c4 + 0][r] = a4.x;
            As[c4 + 1][r] = a4.y;
            As[c4 + 2][r] = a4.z;
            As[c4 + 3][r] = a4.w;
        }
        // ---- stage B (32 k x 128 cols) ----
#pragma unroll
        for (int q = 0; q < 4; q++) {
            const int r  = (tid >> 5) + q * 8;        // 0..31
            const int c4 = (tid & 31) * 4;            // 0..124
            *reinterpret_cast<float4*>(&Bs[r][c4]) =
                *reinterpret_cast<const float4*>(&Wb[(size_t)(kt + r) * N + c4]);
        }
        __syncthreads();

#pragma unroll
        for (int k = 0; k < GM_BK; k++) {
            float a[8], b[8];
#pragma unroll
            for (int i = 0; i < 4; i++) {
                a[i]     = As[k][ty * 4 + i];
                a[4 + i] = As[k][64 + ty * 4 + i];
            }
#pragma unroll
            for (int j = 0; j < 4; j++) {
                b[j]     = Bs[k][tx * 4 + j];
                b[4 + j] = Bs[k][64 + tx * 4 + j];
            }
#pragma unroll
            for (int i = 0; i < 8; i++)
#pragma unroll
                for (int j = 0; j < 8; j++)
                    acc[i][j] = fmaf(a[i], b[j], acc[i][j]);
        }
        __syncthreads();
    }

#pragma unroll
    for (int i = 0; i < 8; i++) {
        const int mr = bm * 128 + ((i < 4) ? (ty * 4 + i) : (64 + ty * 4 + (i - 4)));
        float* Crow = U + (size_t)mr * N + bn * 128;
        float4 v0 = make_float4(acc[i][0], acc[i][1], acc[i][2], acc[i][3]);
        float4 v1 = make_float4(acc[i][4], acc[i][5], acc[i][6], acc[i][7]);
        *reinterpret_cast<float4*>(&Crow[tx * 4])      = v0;
        *reinterpret_cast<float4*>(&Crow[64 + tx * 4]) = v1;
    }
}

// ---------------------------------------------------------------------------
// Kernel 2: sequential ESN recurrence, v11 = r9 (verified best) + two
// serial-chain micro-cuts:
//   (a) leak term v[j] carried in a REGISTER across steps (producer thread is
//       the same every step) -> removes a dependent ~120cy LDS read between
//       the reduce and the critical slot store.
//   (b) u-load moved AFTER the barrier: its LLC latency hides under the MAC
//       instead of folding into the poll's vmcnt wait.
// Structure unchanged: 64 blocks x 256 thr, 32 cols/block, GRP=8, W entries
// in registers + bank-rotation sort, tagged-slot exchange {tag,value},
// double-buffered vsh, single barrier per step, fast tanh.
// Reuse invariant: producing v_{t+1} requires having read all of v_t =>
// parity-buffer overwrite is safe; vsh parity (t&1) + barrier covers LDS.
// ---------------------------------------------------------------------------
#define RB   64    // blocks (1 per CU, trivially co-resident)
#define CPB  32    // columns per block
#define GRP  8     // lanes per column
#define CAP  288   // nnz capacity per column (mean 204.8, sigma 13.6 -> +6.1s)
#define KMAX (CAP / GRP)   // 36 register entries per lane

__device__ __forceinline__ float fast_tanh(float x) {
    const float ax = fabsf(x);
    const float e  = __expf(2.0f * ax);               // inf for big ax
    const float r  = __builtin_amdgcn_rcpf(e + 1.0f); // rcp(inf)=0 -> tanh=1
    const float t  = 1.0f - 2.0f * r;
    return copysignf(t, x);
}

__global__ __launch_bounds__(256, 1) void esn_recur(const float* __restrict__ W,
                                                    float* __restrict__ UO,
                                                    unsigned long long* vslots) {
    __shared__ unsigned long long ent[CPB][CAP];  // setup scratch only
    __shared__ int   cnts[CPB];
    __shared__ float vsh[2][N_OUT];               // double-buffered state

    const int tid = threadIdx.x;
    const int b   = blockIdx.x;
    const int c   = tid >> 3;              // column group 0..31
    const int l   = tid & 7;               // lane within group
    const int j   = b * CPB + c;           // global output column
    const int lw  = tid & 63;              // lane within wave (bank rotation)

    // ---------- build sparse column into LDS scratch (one-time) ----------
    int cnt = 0;
    for (int k = 0; k < N_OUT / GRP; k++) {
        const float w = W[(size_t)(l + GRP * k) * N_OUT + j];
        cnt += (w != 0.0f) ? 1 : 0;
    }
    int inc = cnt;
#pragma unroll
    for (int d = 1; d < GRP; d <<= 1) {
        int n = __shfl_up(inc, d, 64);
        if (l >= d) inc += n;
    }
    int pos = inc - cnt;
    if (l == GRP - 1) cnts[c] = inc;
    for (int k = 0; k < N_OUT / GRP; k++) {
        const int i = l + GRP * k;
        const float w = W[(size_t)i * N_OUT + j];
        if (w != 0.0f) {
            if (pos < CAP)
                ent[c][pos] = ((unsigned long long)(unsigned)i << 32) | __float_as_uint(w);
            pos++;
        }
    }
    __syncthreads();
    const int ccnt = min(cnts[c], CAP);

    // ---------- this lane's entries -> registers, padded to KMAX ----------
    float wreg[KMAX];
    int   ireg[KMAX];
#pragma unroll
    for (int k = 0; k < KMAX; k++) {
        const int p = l + k * GRP;
        if (p < ccnt) {
            const unsigned long long e = ent[c][p];
            wreg[k] = __uint_as_float((unsigned)e);
            ireg[k] = (int)(e >> 32);
        } else {
            wreg[k] = 0.f;   // pad: gathers vsh[0] (same-addr broadcast), w=0
            ireg[k] = 0;
        }
    }

    // ---------- bank-rotation sort (odd-even transposition, deterministic) --
#pragma unroll
    for (int pass = 0; pass < KMAX; ++pass) {
#pragma unroll
        for (int i = (pass & 1); i + 1 < KMAX; i += 2) {
            const int ka = ((ireg[i]     & 31) - lw) & 31;
            const int kb = ((ireg[i + 1] & 31) - lw) & 31;
            const bool sw = ka > kb;
            const int   ti = sw ? ireg[i] : ireg[i + 1];
            const int   bi = sw ? ireg[i + 1] : ireg[i];
            const float tw = sw ? wreg[i] : wreg[i + 1];
            const float bw = sw ? wreg[i + 1] : wreg[i];
            ireg[i] = bi; ireg[i + 1] = ti;
            wreg[i] = bw; wreg[i + 1] = tw;
        }
    }

    float vold = 0.f;   // (a) leak-term state carried in a register

    // ---------- sequential scan over T ----------
#pragma unroll 1
    for (int t = 0; t < T_STEPS; t++) {
        // ---- poll tagged slots for v_t (8 slots/thread, pending-only) -----
        unsigned long long* vin = vslots + (size_t)(t & 1) * N_OUT;
        float* dst = vsh[t & 1];
        unsigned long long uq[8];
#pragma unroll
        for (int q = 0; q < 8; q++)
            uq[q] = __hip_atomic_load(&vin[tid + q * 256], __ATOMIC_RELAXED,
                                      __HIP_MEMORY_SCOPE_AGENT);
        unsigned pend = 0xFFu;
#pragma unroll 1
        while (true) {
            unsigned np = 0;
#pragma unroll
            for (int q = 0; q < 8; q++) {
                if (pend & (1u << q)) {
                    if ((unsigned)(uq[q] >> 32) == (unsigned)t)
                        dst[tid + q * 256] = __uint_as_float((unsigned)uq[q]);
                    else
                        np |= (1u << q);
                }
            }
            pend = np;
            if (!pend) break;
#pragma unroll
            for (int q = 0; q < 8; q++)
                if (pend & (1u << q))
                    uq[q] = __hip_atomic_load(&vin[tid + q * 256], __ATOMIC_RELAXED,
                                              __HIP_MEMORY_SCOPE_AGENT);
        }
        __syncthreads();   // vsh[t&1] complete (single barrier per step)

        // (b) u load AFTER the barrier: hides under the MAC, not the poll
        float u = 0.f;
        if (l == 0) u = UO[(size_t)t * N_OUT + j];

        // ---- MAC from registers: 36 bank-scheduled LDS gathers, 4 accums --
        const float* vcur = vsh[t & 1];
        float y0 = 0.f, y1 = 0.f, y2 = 0.f, y3 = 0.f;
#pragma unroll
        for (int k = 0; k < KMAX; k += 4) {
            y0 = fmaf(wreg[k + 0], vcur[ireg[k + 0]], y0);
            y1 = fmaf(wreg[k + 1], vcur[ireg[k + 1]], y1);
            y2 = fmaf(wreg[k + 2], vcur[ireg[k + 2]], y2);
            y3 = fmaf(wreg[k + 3], vcur[ireg[k + 3]], y3);
        }
        float y = (y0 + y1) + (y2 + y3);
#pragma unroll
        for (int d = GRP / 2; d >= 1; d >>= 1) y += __shfl_xor(y, d, 64);

        if (l == 0) {
            const float vnew = 0.5f * vold + 0.5f * fast_tanh(y + u);
            vold = vnew;
            // slot store FIRST (inter-block critical path), then the output
            const unsigned long long slot =
                ((unsigned long long)(unsigned)(t + 1) << 32) | __float_as_uint(vnew);
            __hip_atomic_store(&vslots[(size_t)((t + 1) & 1) * N_OUT + j], slot,
                               __ATOMIC_RELAXED, __HIP_MEMORY_SCOPE_AGENT);
            UO[(size_t)t * N_OUT + j] = vnew;
        }
        // no trailing barrier: next step touches only vsh[(t+1)&1]
    }
}

// ---------------------------------------------------------------------------
extern "C" void kernel_launch(void* const* d_in, const int* in_sizes, int n_in,
                              void* d_out, int out_size, void* d_ws, size_t ws_size,
                              hipStream_t stream) {
    const float* x   = (const float*)d_in[0];   // [4096, 8192]
    const float* W   = (const float*)d_in[1];   // [2048, 2048]
    const float* Win = (const float*)d_in[2];   // [8192, 2048]
    float* out = (float*)d_out;                 // [4096, 2048]

    unsigned long long* vslots = (unsigned long long*)d_ws;  // 2 x N_OUT x 8B

    // zero tags+values: slot[0] becomes {tag=0, v=0} == the ESN zero state
    hipMemsetAsync(d_ws, 0, 2 * N_OUT * sizeof(unsigned long long), stream);

    dim3 ggrid(T_STEPS / 128, N_OUT / 128);
    gemm_xwin<<<ggrid, 256, 0, stream>>>(x, Win, out);

    esn_recur<<<RB, 256, 0, stream>>>(W, out, vslots);
}

// Round 12
// 11167.104 us; speedup vs baseline: 1.2879x; 1.1489x over previous
//
#include <hip/hip_runtime.h>
#include <hip/hip_bf16.h>
#include <math.h>

// Problem constants (fixed by the reference)
#define T_STEPS 4096
#define N_IN    8192
#define N_OUT   2048

// ---------------------------------------------------------------------------
// FUSED kernel, v12. Blocks [0,64) = ESN recurrence (r9-verbatim hot loop +
// register leak term). Blocks [64,576) = u_proj GEMM (BK=32, 128x128).
//   - r10 spill bug fixed: __launch_bounds__(256,1) -> no VGPR cap; esn path
//     keeps wreg/ireg in registers (expect ~132 VGPR, WRITE_SIZE ~100MB).
//   - Occupancy: esn blocks LDS-bound (90.2KB -> 1/CU); GEMM blocks (33.8KB)
//     fill remaining CUs at 2-3/CU. GEMM finishes ~2ms << esn's 10.3ms.
//   - GEMM m-tile bm completion -> mcnt[bm] (RELEASE-agent RMW after
//     __syncthreads drains vmcnt). esn gates on mcnt[t>>7]==16 (uniform,
//     only at 128-step boundaries, almost always already satisfied).
//   - Deadlock-free: GEMM blocks never spin => queued blocks always drain =>
//     all 64 esn blocks eventually co-resident; esn spin only on esn+mcnt.
//   - r11 lesson kept: u-load issued BEFORE the poll (prefetch riding the
//     poll's wait); r11's after-barrier placement cost ~1ms.
// ---------------------------------------------------------------------------
#define RB    64    // esn blocks
#define CPB   32    // columns per esn block
#define GRP   8     // lanes per column
#define CAP   288   // nnz capacity per column (mean 204.8, sigma 13.6)
#define KMAX  (CAP / GRP)   // 36 register entries per lane
#define NMT   32    // m-tiles (4096/128)
#define GEMM_BLOCKS 512     // 32 m-tiles x 16 n-tiles
#define GM_BK 32

// ---- shared-memory overlay (roles never coexist within a block) ----------
#define SM_ENT   0                        // u64 ent[CPB][CAP] = 73728 B
#define SM_CNTS  73728                    // int cnts[CPB] (+pad) = 128 B
#define SM_VSH   (73728 + 128)            // f32 vsh[2][N_OUT] = 16384 B
#define SM_BYTES (73728 + 128 + 16384)    // 90240 B
#define SM_GA    0                        // f32 As[32][132] = 16896 B
#define SM_GB    16896                    // f32 Bs[32][132] = 16896 B

__device__ __forceinline__ float fast_tanh(float x) {
    const float ax = fabsf(x);
    const float e  = __expf(2.0f * ax);               // inf for big ax
    const float r  = __builtin_amdgcn_rcpf(e + 1.0f); // rcp(inf)=0 -> tanh=1
    const float t  = 1.0f - 2.0f * r;
    return copysignf(t, x);
}

__global__ __launch_bounds__(256, 1) void esn_fused(
        const float* __restrict__ X,    // [4096, 8192]
        const float* __restrict__ W,    // [2048, 2048]
        const float* __restrict__ Win,  // [8192, 2048]
        float* __restrict__ UO,         // [4096, 2048] u_proj then states
        unsigned long long* vslots,     // 2 x N_OUT tagged slots
        int* mcnt) {                    // NMT m-tile completion counters
    __shared__ __align__(16) char smem[SM_BYTES];
    const int tid = threadIdx.x;

    if (blockIdx.x >= RB) {
        // =================== GEMM role (u_proj = X @ Win) ===================
        float (*As)[132] = reinterpret_cast<float(*)[132]>(smem + SM_GA);
        float (*Bs)[132] = reinterpret_cast<float(*)[132]>(smem + SM_GB);
        const int gb = (int)blockIdx.x - RB;
        const int bm = gb >> 4;            // blocks 64..79 are m-tile 0 (first)
        const int bn = gb & 15;
        const int K = N_IN, N = N_OUT;
        const int tx = tid & 15;
        const int ty = tid >> 4;

        float acc[8][8];
#pragma unroll
        for (int i = 0; i < 8; i++)
#pragma unroll
            for (int jj = 0; jj < 8; jj++) acc[i][jj] = 0.f;

        const float* Xb = X + (size_t)(bm * 128) * K;
        const float* Wb = Win + bn * 128;

        for (int kt = 0; kt < K; kt += GM_BK) {
#pragma unroll
            for (int q = 0; q < 4; q++) {
                const int r  = (tid >> 3) + q * 32;
                const int c4 = (tid & 7) * 4;
                const float4 a4 = *reinterpret_cast<const float4*>(&Xb[(size_t)r * K + kt + c4]);
                As[c4 + 0][r] = a4.x;
                As[c4 + 1][r] = a4.y;
                As[c4 + 2][r] = a4.z;
                As[c4 + 3][r] = a4.w;
            }
#pragma unroll
            for (int q = 0; q < 4; q++) {
                const int r  = (tid >> 5) + q * 8;
                const int c4 = (tid & 31) * 4;
                *reinterpret_cast<float4*>(&Bs[r][c4]) =
                    *reinterpret_cast<const float4*>(&Wb[(size_t)(kt + r) * N + c4]);
            }
            __syncthreads();

#pragma unroll
            for (int k = 0; k < GM_BK; k++) {
                float a[8], bb[8];
#pragma unroll
                for (int i = 0; i < 4; i++) {
                    a[i]     = As[k][ty * 4 + i];
                    a[4 + i] = As[k][64 + ty * 4 + i];
                }
#pragma unroll
                for (int jj = 0; jj < 4; jj++) {
                    bb[jj]     = Bs[k][tx * 4 + jj];
                    bb[4 + jj] = Bs[k][64 + tx * 4 + jj];
                }
#pragma unroll
                for (int i = 0; i < 8; i++)
#pragma unroll
                    for (int jj = 0; jj < 8; jj++)
                        acc[i][jj] = fmaf(a[i], bb[jj], acc[i][jj]);
            }
            __syncthreads();
        }

#pragma unroll
        for (int i = 0; i < 8; i++) {
            const int mr = bm * 128 + ((i < 4) ? (ty * 4 + i) : (64 + ty * 4 + (i - 4)));
            float* Crow = UO + (size_t)mr * N + bn * 128;
            float4 v0 = make_float4(acc[i][0], acc[i][1], acc[i][2], acc[i][3]);
            float4 v1 = make_float4(acc[i][4], acc[i][5], acc[i][6], acc[i][7]);
            *reinterpret_cast<float4*>(&Crow[tx * 4])      = v0;
            *reinterpret_cast<float4*>(&Crow[64 + tx * 4]) = v1;
        }
        __syncthreads();   // compiler drains vmcnt(0) before s_barrier
        if (tid == 0)      // release makes the C-tile visible, then signals
            __hip_atomic_fetch_add(&mcnt[bm], 1, __ATOMIC_RELEASE,
                                   __HIP_MEMORY_SCOPE_AGENT);
        return;
    }

    // ======================= ESN recurrence role (r9) =======================
    __builtin_amdgcn_s_setprio(1);   // esn waves win issue arbitration
    auto ent  = reinterpret_cast<unsigned long long(*)[CAP]>(smem + SM_ENT);
    int* cnts = reinterpret_cast<int*>(smem + SM_CNTS);
    float (*vsh)[N_OUT] = reinterpret_cast<float(*)[N_OUT]>(smem + SM_VSH);

    const int b   = blockIdx.x;
    const int c   = tid >> 3;              // column group 0..31
    const int l   = tid & 7;               // lane within group
    const int j   = b * CPB + c;           // global output column
    const int lw  = tid & 63;              // lane within wave (bank rotation)

    // ---------- build sparse column into LDS scratch (one-time) ----------
    int cnt = 0;
    for (int k = 0; k < N_OUT / GRP; k++) {
        const float w = W[(size_t)(l + GRP * k) * N_OUT + j];
        cnt += (w != 0.0f) ? 1 : 0;
    }
    int inc = cnt;
#pragma unroll
    for (int d = 1; d < GRP; d <<= 1) {
        int n = __shfl_up(inc, d, 64);
        if (l >= d) inc += n;
    }
    int pos = inc - cnt;
    if (l == GRP - 1) cnts[c] = inc;
    for (int k = 0; k < N_OUT / GRP; k++) {
        const int i = l + GRP * k;
        const float w = W[(size_t)i * N_OUT + j];
        if (w != 0.0f) {
            if (pos < CAP)
                ent[c][pos] = ((unsigned long long)(unsigned)i << 32) | __float_as_uint(w);
            pos++;
        }
    }
    __syncthreads();
    const int ccnt = min(cnts[c], CAP);

    // ---------- this lane's entries -> registers, padded to KMAX ----------
    float wreg[KMAX];
    int   ireg[KMAX];
#pragma unroll
    for (int k = 0; k < KMAX; k++) {
        const int p = l + k * GRP;
        if (p < ccnt) {
            const unsigned long long e = ent[c][p];
            wreg[k] = __uint_as_float((unsigned)e);
            ireg[k] = (int)(e >> 32);
        } else {
            wreg[k] = 0.f;   // pad: gathers vsh[0] (same-addr broadcast), w=0
            ireg[k] = 0;
        }
    }

    // ---------- bank-rotation sort (odd-even transposition, deterministic) --
#pragma unroll
    for (int pass = 0; pass < KMAX; ++pass) {
#pragma unroll
        for (int i = (pass & 1); i + 1 < KMAX; i += 2) {
            const int ka = ((ireg[i]     & 31) - lw) & 31;
            const int kb = ((ireg[i + 1] & 31) - lw) & 31;
            const bool sw = ka > kb;
            const int   ti = sw ? ireg[i] : ireg[i + 1];
            const int   bi = sw ? ireg[i + 1] : ireg[i];
            const float tw = sw ? wreg[i] : wreg[i + 1];
            const float bw = sw ? wreg[i + 1] : wreg[i];
            ireg[i] = bi; ireg[i + 1] = ti;
            wreg[i] = bw; wreg[i + 1] = tw;
        }
    }

    float vold = 0.f;   // leak-term state carried in a register

    // ---------- sequential scan over T ----------
#pragma unroll 1
    for (int t = 0; t < T_STEPS; t++) {
        // gate on the u-producer once per m-tile (uniform, rare, usually open)
        if ((t & 127) == 0) {
            while (__hip_atomic_load(&mcnt[t >> 7], __ATOMIC_ACQUIRE,
                                     __HIP_MEMORY_SCOPE_AGENT) < 16) { }
        }
        // u prefetch BEFORE the poll: its latency rides the poll's wait (r11)
        float u = 0.f;
        if (l == 0) u = UO[(size_t)t * N_OUT + j];

        // ---- poll tagged slots for v_t (8 slots/thread, pending-only) -----
        unsigned long long* vin = vslots + (size_t)(t & 1) * N_OUT;
        float* dst = vsh[t & 1];
        unsigned long long uq[8];
#pragma unroll
        for (int q = 0; q < 8; q++)
            uq[q] = __hip_atomic_load(&vin[tid + q * 256], __ATOMIC_RELAXED,
                                      __HIP_MEMORY_SCOPE_AGENT);
        unsigned pend = 0xFFu;
#pragma unroll 1
        while (true) {
            unsigned np = 0;
#pragma unroll
            for (int q = 0; q < 8; q++) {
                if (pend & (1u << q)) {
                    if ((unsigned)(uq[q] >> 32) == (unsigned)t)
                        dst[tid + q * 256] = __uint_as_float((unsigned)uq[q]);
                    else
                        np |= (1u << q);
                }
            }
            pend = np;
            if (!pend) break;
#pragma unroll
            for (int q = 0; q < 8; q++)
                if (pend & (1u << q))
                    uq[q] = __hip_atomic_load(&vin[tid + q * 256], __ATOMIC_RELAXED,
                                              __HIP_MEMORY_SCOPE_AGENT);
        }
        __syncthreads();   // vsh[t&1] complete (single barrier per step)

        // ---- MAC from registers: 36 bank-scheduled LDS gathers, 4 accums --
        const float* vcur = vsh[t & 1];
        float y0 = 0.f, y1 = 0.f, y2 = 0.f, y3 = 0.f;
#pragma unroll
        for (int k = 0; k < KMAX; k += 4) {
            y0 = fmaf(wreg[k + 0], vcur[ireg[k + 0]], y0);
            y1 = fmaf(wreg[k + 1], vcur[ireg[k + 1]], y1);
            y2 = fmaf(wreg[k + 2], vcur[ireg[k + 2]], y2);
            y3 = fmaf(wreg[k + 3], vcur[ireg[k + 3]], y3);
        }
        float y = (y0 + y1) + (y2 + y3);
#pragma unroll
        for (int d = GRP / 2; d >= 1; d >>= 1) y += __shfl_xor(y, d, 64);

        if (l == 0) {
            const float vnew = 0.5f * vold + 0.5f * fast_tanh(y + u);
            vold = vnew;
            // slot store FIRST (inter-block critical path), then the output
            const unsigned long long slot =
                ((unsigned long long)(unsigned)(t + 1) << 32) | __float_as_uint(vnew);
            __hip_atomic_store(&vslots[(size_t)((t + 1) & 1) * N_OUT + j], slot,
                               __ATOMIC_RELAXED, __HIP_MEMORY_SCOPE_AGENT);
            UO[(size_t)t * N_OUT + j] = vnew;
        }
        // no trailing barrier: next step touches only vsh[(t+1)&1]
        // (producing v_{t+1} requires all of v_t read -> parity reuse safe)
    }
}

// ---------------------------------------------------------------------------
extern "C" void kernel_launch(void* const* d_in, const int* in_sizes, int n_in,
                              void* d_out, int out_size, void* d_ws, size_t ws_size,
                              hipStream_t stream) {
    const float* x   = (const float*)d_in[0];   // [4096, 8192]
    const float* W   = (const float*)d_in[1];   // [2048, 2048]
    const float* Win = (const float*)d_in[2];   // [8192, 2048]
    float* out = (float*)d_out;                 // [4096, 2048]

    unsigned long long* vslots = (unsigned long long*)d_ws;  // 2 x N_OUT x 8B
    int* mcnt = (int*)((char*)d_ws + 2 * N_OUT * sizeof(unsigned long long));

    // zero slots (tag0 = zero state) + m-tile counters, every launch
    hipMemsetAsync(d_ws, 0,
                   2 * N_OUT * sizeof(unsigned long long) + NMT * sizeof(int),
                   stream);

    esn_fused<<<RB + GEMM_BLOCKS, 256, 0, stream>>>(x, W, Win, out, vslots, mcnt);
}